// Round 22
// baseline (150.035 us; speedup 1.0000x reference)
//
#include <hip/hip_runtime.h>
#include <hip/hip_bf16.h>

#define B_     8
#define N_     1024
#define DIM_   1024
#define HEADS_ 16
#define DH_    64
#define INNER_ 1024
#define NKEY_  1025
#define NTILE_ 34        // kv tiles of 32 keys (33 real + 1 phantom zero tile)
#define NW_    34        // vbits words per batch (word 33 = 0)
#define ROWS_  8192
#define EPS_   1e-5f
// DIM_HEAD^-0.5 * log2(e): softmax done in exp2 domain; ALPHA/pb-relax cancels
#define QK_SCALE_ 0.1803368801111f
#define TILE_ELEMS_ 4096   // per (b,kt): 2048 K [j][d] + 2048 V^T [d][j]

typedef unsigned short u16;
typedef unsigned char  u8;
typedef unsigned int   u32;
typedef __attribute__((ext_vector_type(8)))  short bf16x8;
typedef __attribute__((ext_vector_type(4)))  float f32x4;
typedef __attribute__((ext_vector_type(16))) float f32x16;

__device__ __forceinline__ float bf2f(u16 u) {
    unsigned int x = ((unsigned int)u) << 16;
    return __uint_as_float(x);
}
__device__ __forceinline__ u16 f2bf(float f) {
    unsigned int x = __float_as_uint(f);
    x += 0x7FFFu + ((x >> 16) & 1u);   // RNE
    return (u16)(x >> 16);
}
__device__ __forceinline__ float max3f(float a, float b, float c) {
    return fmaxf(fmaxf(a, b), c);      // fuses to v_max3_f32
}
// 2^x via v_exp_f32 (ISA: D = 2^S0). Avoids glibc __exp2f macro collision.
__device__ __forceinline__ float exp2fast(float x) {
    float r;
    asm("v_exp_f32 %0, %1" : "=v"(r) : "v"(x));
    return r;
}

#define MFMA16(a, b, c) __builtin_amdgcn_mfma_f32_16x16x32_bf16((a), (b), (c), 0, 0, 0)
#define MFMA32(a, b, c) __builtin_amdgcn_mfma_f32_32x32x16_bf16((a), (b), (c), 0, 0, 0)

__device__ __forceinline__ void gload16(const void* g, void* l) {
    __builtin_amdgcn_global_load_lds(
        (const __attribute__((address_space(1))) unsigned int*)g,
        (__attribute__((address_space(3))) unsigned int*)l, 16, 0, 0);
}

__device__ __forceinline__ u32 cvtpk(float lo, float hi) {
    u32 r;
    asm("v_cvt_pk_bf16_f32 %0, %1, %2" : "=v"(r) : "v"(lo), "v"(hi));
    return r;
}
__device__ __forceinline__ void plswap(u32& a, u32& b) {
    asm volatile("v_permlane32_swap_b32 %0, %1" : "+v"(a), "+v"(b));
}

// ---------------- fused prep: build_bits (2 blocks) + cvt_w (2176) + ln0 (8192) --
__global__ __launch_bounds__(256)
void prep(const void* __restrict__ mraw, u32* __restrict__ vbits,
          const float* __restrict__ wq, const float* __restrict__ wkv,
          const float* __restrict__ wo, u16* __restrict__ q16,
          u16* __restrict__ kv16, u16* __restrict__ o16,
          const float* __restrict__ x, const float* __restrict__ g_in,
          u16* __restrict__ xn, u16* __restrict__ xb) {
    const int bx = blockIdx.x;
    const int t  = threadIdx.x;
    if (bx < 2) {
        int tid = bx * 256 + t;
        if (tid >= B_ * NW_) return;
        const unsigned int* mw = (const unsigned int*)mraw;
        int f = 0;  // 0=int32, 1=bytes(bool), 2=float32
        for (int i = 0; i < 64; ++i) {
            unsigned int w = mw[i];
            if (w == 0x3F800000u) { f = 2; break; }
            if (w > 1u) f = 1;
        }
        int b = tid / NW_, wq_ = tid - b * NW_;
        u32 bits = 0;
        for (int i = 0; i < 32; ++i) {
            int jp = wq_ * 32 + i;
            bool vis;
            if (jp == 0) vis = true;
            else if (jp < NKEY_) {
                int idx = b * N_ + jp - 1;
                if (f == 0)      vis = ((const int*)mraw)[idx] != 0;
                else if (f == 1) vis = ((const u8*)mraw)[idx] != 0;
                else             vis = ((const float*)mraw)[idx] != 0.0f;
            } else vis = false;
            if (vis) bits |= (1u << i);
        }
        vbits[tid] = bits;
    } else if (bx < 2 + 2176) {
        int i = (bx - 2) * 256 + t;   // unit = 4 elems
        const int NQ = INNER_ * DIM_ / 4, NKV = 128 * DIM_ / 4, NO = DIM_ * INNER_ / 4;
        const float* src; u16* dst; int off;
        if (i < NQ)            { src = wq;  dst = q16;  off = i; }
        else if (i < NQ + NKV) { src = wkv; dst = kv16; off = i - NQ; }
        else if (i < NQ + NKV + NO) { src = wo; dst = o16; off = i - NQ - NKV; }
        else return;
        float4 v = ((const float4*)src)[off];
        ushort4 u; u.x = f2bf(v.x); u.y = f2bf(v.y); u.z = f2bf(v.z); u.w = f2bf(v.w);
        ((ushort4*)dst)[off] = u;
    } else {
        int row = bx - (2 + 2176);
        float4 v = ((const float4*)(x + (size_t)row * DIM_))[t];
        float v0 = v.x, v1 = v.y, v2 = v.z, v3 = v.w;
        float s  = v0 + v1 + v2 + v3;
        float ss = v0*v0 + v1*v1 + v2*v2 + v3*v3;
#pragma unroll
        for (int off = 32; off > 0; off >>= 1) {
            s  += __shfl_down(s,  off, 64);
            ss += __shfl_down(ss, off, 64);
        }
        __shared__ float red[10];
        int wid = t >> 6, lane = t & 63;
        if (lane == 0) { red[wid] = s; red[4 + wid] = ss; }
        __syncthreads();
        if (t == 0) {
            float S  = red[0] + red[1] + red[2] + red[3];
            float SS = red[4] + red[5] + red[6] + red[7];
            float mean = S * (1.0f / DIM_);
            float var  = SS * (1.0f / DIM_) - mean * mean;
            red[8] = mean;
            red[9] = rsqrtf(var + EPS_);
        }
        __syncthreads();
        float mean = red[8], rs = red[9];
        float4 gv = ((const float4*)g_in)[t];
        float o0 = (v0 - mean) * rs * gv.x;
        float o1 = (v1 - mean) * rs * gv.y;
        float o2 = (v2 - mean) * rs * gv.z;
        float o3 = (v3 - mean) * rs * gv.w;
        ushort4 u; u.x = f2bf(o0); u.y = f2bf(o1); u.z = f2bf(o2); u.w = f2bf(o3);
        ((ushort4*)(xn + (size_t)row * DIM_))[t] = u;
        ushort4 rw; rw.x = f2bf(v0); rw.y = f2bf(v1); rw.z = f2bf(v2); rw.w = f2bf(v3);
        ((ushort4*)(xb + (size_t)row * DIM_))[t] = rw;
    }
}

// ---------------- final layernorm: bf16 in -> f32 out ----------------
__global__ __launch_bounds__(256)
void ln_out(const u16* __restrict__ xv, const float* __restrict__ g,
            float* __restrict__ outv) {
    int row = blockIdx.x;
    int t = threadIdx.x;
    ushort4 u = ((const ushort4*)(xv + (size_t)row * DIM_))[t];
    float v0 = bf2f(u.x), v1 = bf2f(u.y), v2 = bf2f(u.z), v3 = bf2f(u.w);
    float s  = v0 + v1 + v2 + v3;
    float ss = v0*v0 + v1*v1 + v2*v2 + v3*v3;
#pragma unroll
    for (int off = 32; off > 0; off >>= 1) {
        s  += __shfl_down(s,  off, 64);
        ss += __shfl_down(ss, off, 64);
    }
    __shared__ float red[10];
    int wid = t >> 6, lane = t & 63;
    if (lane == 0) { red[wid] = s; red[4 + wid] = ss; }
    __syncthreads();
    if (t == 0) {
        float S  = red[0] + red[1] + red[2] + red[3];
        float SS = red[4] + red[5] + red[6] + red[7];
        float mean = S * (1.0f / DIM_);
        float var  = SS * (1.0f / DIM_) - mean * mean;
        red[8] = mean;
        red[9] = rsqrtf(var + EPS_);
    }
    __syncthreads();
    float mean = red[8], rs = red[9];
    float4 gv = ((const float4*)g)[t];
    float4 o;
    o.x = (v0 - mean) * rs * gv.x;
    o.y = (v1 - mean) * rs * gv.y;
    o.z = (v2 - mean) * rs * gv.z;
    o.w = (v3 - mean) * rs * gv.w;
    ((float4*)(outv + (size_t)row * DIM_))[t] = o;
}

// ---------------- fused Q-proj + KV-proj (m97 structure, BK=32, K=1024) ---------
// XCD-chunked remap: id%8 == XCD, each XCD gets 72 consecutive wids -> A-panels
// L2-resident -> staging hits local L2, shortening the vmcnt(0) barrier drain.
__global__ __launch_bounds__(256)
void proj_fused(const u16* __restrict__ xn, const u16* __restrict__ xraw,
                const u16* __restrict__ wq, const u16* __restrict__ wkv,
                u16* __restrict__ qout, float* __restrict__ kvout) {
    __shared__ u16 As[128 * 32];
    __shared__ u16 Bs[128 * 32];
    const int id  = blockIdx.x + 9 * blockIdx.y;      // 0..575
    const int wid = (id & 7) * 72 + (id >> 3);        // bijective (576 = 8*72)
    const int bxx = wid % 9, byy = wid / 9;
    const bool iskv = (bxx == 8);
    const u16* A  = iskv ? xraw : xn;
    const u16* Bt = iskv ? wkv : wq;
    const int  n0 = iskv ? 0 : bxx * 128;
    const float scale = iskv ? 1.0f : QK_SCALE_;
    const int t = threadIdx.x;
    const int w = t >> 6, l = t & 63;
    const int col = l & 15, rg = l >> 4;
    const int wm = (w >> 1) * 64, wn = (w & 1) * 64;
    const int m0 = byy * 128;
    const int slr = l >> 2;
    const int slc = (l & 3) * 8;
    f32x4 acc[4][4];
#pragma unroll
    for (int i = 0; i < 4; ++i)
#pragma unroll
        for (int j = 0; j < 4; ++j) acc[i][j] = f32x4{0.f, 0.f, 0.f, 0.f};

    const u16* Abase = A  + (size_t)m0 * DIM_;
    const u16* Bbase = Bt + (size_t)n0 * DIM_;
    for (int k0 = 0; k0 < DIM_; k0 += 32) {
        __syncthreads();
#pragma unroll
        for (int p = 0; p < 2; ++p) {
            int rb = w * 2 + p;
            gload16(Abase + (size_t)(rb * 16 + slr) * DIM_ + k0 + slc, &As[rb * 512]);
            gload16(Bbase + (size_t)(rb * 16 + slr) * DIM_ + k0 + slc, &Bs[rb * 512]);
        }
        __syncthreads();
        bf16x8 af[4], bf4[4];
#pragma unroll
        for (int mi = 0; mi < 4; ++mi)
            af[mi] = *(const bf16x8*)&As[(wm + mi * 16 + col) * 32 + rg * 8];
#pragma unroll
        for (int ni = 0; ni < 4; ++ni)
            bf4[ni] = *(const bf16x8*)&Bs[(wn + ni * 16 + col) * 32 + rg * 8];
#pragma unroll
        for (int mi = 0; mi < 4; ++mi)
#pragma unroll
            for (int ni = 0; ni < 4; ++ni)
                acc[mi][ni] = MFMA16(af[mi], bf4[ni], acc[mi][ni]);
    }
#pragma unroll
    for (int mi = 0; mi < 4; ++mi)
#pragma unroll
        for (int ni = 0; ni < 4; ++ni)
#pragma unroll
            for (int r = 0; r < 4; ++r) {
                size_t row = (size_t)(m0 + wm + mi * 16 + rg * 4 + r);
                int c = n0 + wn + ni * 16 + col;
                float vv = acc[mi][ni][r] * scale;
                if (iskv) kvout[row * 128 + c] = vv;
                else      qout[row * INNER_ + c] = f2bf(vv);
            }
}

// ---------------- MFMA GEMM for O-projection (BK=32, XCD-chunked remap) --------
__global__ __launch_bounds__(256)
void gemm_o(const u16* __restrict__ A, const u16* __restrict__ Bt,
            u16* __restrict__ Cv) {
    __shared__ u16 As[128 * 32];
    __shared__ u16 Bs[128 * 32];
    const int id  = blockIdx.x + 8 * blockIdx.y;      // 0..511
    const int wid = (id & 7) * 64 + (id >> 3);        // bijective (512 = 8*64)
    const int bxx = wid & 7, byy = wid >> 3;
    const int t = threadIdx.x;
    const int w = t >> 6, l = t & 63;
    const int col = l & 15, rg = l >> 4;
    const int wm = (w >> 1) * 64, wn = (w & 1) * 64;
    const int m0 = byy * 128, n0 = bxx * 128;
    const int slr = l >> 2;
    const int slc = (l & 3) * 8;
    f32x4 acc[4][4];
#pragma unroll
    for (int i = 0; i < 4; ++i)
#pragma unroll
        for (int j = 0; j < 4; ++j) acc[i][j] = f32x4{0.f, 0.f, 0.f, 0.f};
    const u16* Abase = A  + (size_t)m0 * INNER_;
    const u16* Bbase = Bt + (size_t)n0 * INNER_;
    for (int k0 = 0; k0 < INNER_; k0 += 32) {
        __syncthreads();
#pragma unroll
        for (int p = 0; p < 2; ++p) {
            int rb = w * 2 + p;
            gload16(Abase + (size_t)(rb * 16 + slr) * INNER_ + k0 + slc, &As[rb * 512]);
            gload16(Bbase + (size_t)(rb * 16 + slr) * INNER_ + k0 + slc, &Bs[rb * 512]);
        }
        __syncthreads();
        bf16x8 af[4], bf4[4];
#pragma unroll
        for (int mi = 0; mi < 4; ++mi)
            af[mi] = *(const bf16x8*)&As[(wm + mi * 16 + col) * 32 + rg * 8];
#pragma unroll
        for (int ni = 0; ni < 4; ++ni)
            bf4[ni] = *(const bf16x8*)&Bs[(wn + ni * 16 + col) * 32 + rg * 8];
#pragma unroll
        for (int mi = 0; mi < 4; ++mi)
#pragma unroll
            for (int ni = 0; ni < 4; ++ni)
                acc[mi][ni] = MFMA16(af[mi], bf4[ni], acc[mi][ni]);
    }
#pragma unroll
    for (int mi = 0; mi < 4; ++mi)
#pragma unroll
        for (int ni = 0; ni < 4; ++ni)
#pragma unroll
            for (int r = 0; r < 4; ++r) {
                size_t row = (size_t)(m0 + wm + mi * 16 + rg * 4 + r);
                int c = n0 + wn + ni * 16 + col;
                Cv[row * DIM_ + c] = f2bf(acc[mi][ni][r]);
            }
}

// ---------------- build per-tile K/V: [b][kt]{ K[32][64], V^T[64][32] } ----------------
__global__ __launch_bounds__(256)
void build_kv(const float* __restrict__ kvf, const float* __restrict__ nullkv,
              u16* __restrict__ KVt) {
    const int kt = blockIdx.x, b = blockIdx.y;
    const int t = threadIdx.x;
    const int k0 = kt * 32;
    u16* base = KVt + ((size_t)b * NTILE_ + kt) * TILE_ELEMS_;
    // K part: [j][d], 8 elems/thread, contiguous dest
    {
        int j = t >> 3;
        int d0 = (t & 7) * 8;
        int jp = k0 + j;
        float v[8];
        if (jp == 0) {
#pragma unroll
            for (int i = 0; i < 8; ++i) v[i] = nullkv[d0 + i];
        } else if (jp <= N_) {
            const float* r = kvf + ((size_t)b * N_ + jp - 1) * 128 + d0;
            float4 a = ((const float4*)r)[0], c = ((const float4*)r)[1];
            v[0]=a.x; v[1]=a.y; v[2]=a.z; v[3]=a.w; v[4]=c.x; v[5]=c.y; v[6]=c.z; v[7]=c.w;
        } else {
#pragma unroll
            for (int i = 0; i < 8; ++i) v[i] = 0.f;
        }
        ushort4 u0, u1;
        u0.x=f2bf(v[0]); u0.y=f2bf(v[1]); u0.z=f2bf(v[2]); u0.w=f2bf(v[3]);
        u1.x=f2bf(v[4]); u1.y=f2bf(v[5]); u1.z=f2bf(v[6]); u1.w=f2bf(v[7]);
        *(ushort4*)(base + j * 64 + d0)     = u0;
        *(ushort4*)(base + j * 64 + d0 + 4) = u1;
    }
    // V part: [d][j], 8 elems/thread (8 consecutive j for one d)
    {
        int d = t >> 2;
        int j0 = (t & 3) * 8;
        u16 o8[8];
#pragma unroll
        for (int i = 0; i < 8; ++i) {
            int jp = k0 + j0 + i;
            float val = 0.f;
            if (jp == 0) val = nullkv[64 + d];
            else if (jp <= N_) val = kvf[((size_t)b * N_ + jp - 1) * 128 + 64 + d];
            o8[i] = f2bf(val);
        }
        u16* dst = base + 2048 + d * 32 + j0;
        ushort4 u0, u1;
        u0.x=o8[0]; u0.y=o8[1]; u0.z=o8[2]; u0.w=o8[3];
        u1.x=o8[4]; u1.y=o8[5]; u1.z=o8[6]; u1.w=o8[7];
        *(ushort4*)dst = u0;
        *(ushort4*)(dst + 4) = u1;
    }
}

// ---------------- unpaired no-LDS flash attention, KVBLK=64, exp2 softmax -------
// XCD-affinity: b = fid & 7; LPT: qt = 31 - (fid>>5).
// NEW: K fragments for superstep st+1 are register-prefetched while st computes
// (T14: hide ~300cy L2 latency under the ~600cy MFMA+softmax compute phase).
__global__ __launch_bounds__(256)
void attn_un(const u16* __restrict__ Q, const u16* __restrict__ KVt,
             const u32* __restrict__ vbits, u16* __restrict__ Out) {
    const int t = threadIdx.x;
    const int w = t >> 6, l = t & 63;
    const int lo = l & 31, hi = l >> 5;
    const int fid = blockIdx.x;
    const int b  = fid & 7;                   // == XCD id (blockIdx % 8)
    const int hg = (fid >> 3) & 3;
    const int qt = 31 - (fid >> 5);           // longest first (LPT)
    const int h = hg * 4 + w;
    const int i0 = qt * 32;
    const int nst = (qt + 3) >> 1;            // super-steps of 64 keys

    bf16x8 qf[4];
    {
        const u16* qp = Q + ((size_t)(b * N_ + i0 + lo)) * INNER_ + h * DH_ + hi * 8;
#pragma unroll
        for (int dt = 0; dt < 4; ++dt) qf[dt] = *(const bf16x8*)(qp + dt * 16);
    }
    f32x16 o0, o1;
#pragma unroll
    for (int i = 0; i < 16; ++i) { o0[i] = 0.f; o1[i] = 0.f; }
    float m = -3.0e38f, lsum = 0.f;

    const u16* tbase = KVt + (size_t)b * NTILE_ * TILE_ELEMS_;
    const u32* vbp = vbits + b * NW_;
    const int koff  = lo * 64 + hi * 8;
    const int voff0 = 2048 + lo * 32 + hi * 8;
    const int voff1 = 2048 + (lo + 32) * 32 + hi * 8;

#define LOADK(ST, K0, K1) do { \
        const u16* tbk0_ = tbase + (size_t)((ST) * 2)     * TILE_ELEMS_; \
        const u16* tbk1_ = tbase + (size_t)((ST) * 2 + 1) * TILE_ELEMS_; \
        K0[0] = *(const bf16x8*)(tbk0_ + koff); \
        K0[1] = *(const bf16x8*)(tbk0_ + koff + 16); \
        K0[2] = *(const bf16x8*)(tbk0_ + koff + 32); \
        K0[3] = *(const bf16x8*)(tbk0_ + koff + 48); \
        K1[0] = *(const bf16x8*)(tbk1_ + koff); \
        K1[1] = *(const bf16x8*)(tbk1_ + koff + 16); \
        K1[2] = *(const bf16x8*)(tbk1_ + koff + 32); \
        K1[3] = *(const bf16x8*)(tbk1_ + koff + 48); \
    } while (0)

    auto step = [&](int st, const bf16x8* kf0, const bf16x8* kf1) {
        const int kt0 = st * 2, kt1 = st * 2 + 1;
        const u16* tb0 = tbase + (size_t)kt0 * TILE_ELEMS_;
        const u16* tb1 = tbase + (size_t)kt1 * TILE_ELEMS_;

        u32 vb0 = vbp[kt0], vb1 = vbp[kt1];
        union { u32 wd[4]; bf16x8 v; } bias0, bias1, ones;
        bias0.wd[0] = (hi == 0 && !((vb0 >> lo) & 1u)) ? 0xC6E0u : 0u; // bf16 -28672
        bias0.wd[1] = 0; bias0.wd[2] = 0; bias0.wd[3] = 0;
        bias1.wd[0] = (hi == 0 && !((vb1 >> lo) & 1u)) ? 0xC6E0u : 0u;
        bias1.wd[1] = 0; bias1.wd[2] = 0; bias1.wd[3] = 0;
        ones.wd[0] = (hi == 0) ? 0x3F80u : 0u;                         // bf16 1.0
        ones.wd[1] = 0; ones.wd[2] = 0; ones.wd[3] = 0;

        f32x16 s0, s1;
        __builtin_amdgcn_s_setprio(1);
#pragma unroll
        for (int i = 0; i < 16; ++i) { s0[i] = 0.f; s1[i] = 0.f; }
        s0 = MFMA32(kf0[0], qf[0], s0);
        s1 = MFMA32(kf1[0], qf[0], s1);
        s0 = MFMA32(kf0[1], qf[1], s0);
        s1 = MFMA32(kf1[1], qf[1], s1);
        s0 = MFMA32(kf0[2], qf[2], s0);
        s1 = MFMA32(kf1[2], qf[2], s1);
        s0 = MFMA32(kf0[3], qf[3], s0);
        s1 = MFMA32(kf1[3], qf[3], s1);
        s0 = MFMA32(bias0.v, ones.v, s0);
        s1 = MFMA32(bias1.v, ones.v, s1);
        __builtin_amdgcn_s_setprio(0);

        // ---- one softmax pass over 32 scores ----
        float t0 = max3f(s0[0],  s0[1],  s0[2]);
        float t1 = max3f(s0[3],  s0[4],  s0[5]);
        float t2 = max3f(s0[6],  s0[7],  s0[8]);
        float t3 = max3f(s0[9],  s0[10], s0[11]);
        float t4 = max3f(s0[12], s0[13], s0[14]);
        float u0 = max3f(s1[0],  s1[1],  s1[2]);
        float u1 = max3f(s1[3],  s1[4],  s1[5]);
        float u2 = max3f(s1[6],  s1[7],  s1[8]);
        float u3 = max3f(s1[9],  s1[10], s1[11]);
        float u4 = max3f(s1[12], s1[13], s1[14]);
        float mt = fmaxf(max3f(max3f(t0, t1, t2), max3f(t3, t4, s0[15]),
                               max3f(u0, u1, u2)),
                         max3f(u3, u4, s1[15]));
        mt = fmaxf(mt, __shfl_xor(mt, 32, 64));
        if (!__all(mt <= m + 8.0f)) {          // defer-max (T13), exp2 domain
            float mn = fmaxf(m, mt);
            float c = exp2fast(m - mn);
            lsum *= c;
#pragma unroll
            for (int i = 0; i < 16; ++i) { o0[i] *= c; o1[i] *= c; }
            m = mn;
        }
        float p0[16], p1[16];
#pragma unroll
        for (int r = 0; r < 16; ++r) p0[r] = exp2fast(s0[r] - m);
#pragma unroll
        for (int r = 0; r < 16; ++r) p1[r] = exp2fast(s1[r] - m);
        if (kt0 >= qt) {
            int lim0 = i0 + lo + 1 - kt0 * 32 - 4 * hi;
#pragma unroll
            for (int r = 0; r < 16; ++r)
                if (((r & 3) + 8 * (r >> 2)) > lim0) p0[r] = 0.f;
        }
        if (kt1 >= qt) {
            int lim1 = i0 + lo + 1 - kt1 * 32 - 4 * hi;
#pragma unroll
            for (int r = 0; r < 16; ++r)
                if (((r & 3) + 8 * (r >> 2)) > lim1) p1[r] = 0.f;
        }
        float ls = ((((p0[0]+p0[1])+(p0[2]+p0[3])) + ((p0[4]+p0[5])+(p0[6]+p0[7])))
                 +  (((p0[8]+p0[9])+(p0[10]+p0[11])) + ((p0[12]+p0[13])+(p0[14]+p0[15]))))
                 + ((((p1[0]+p1[1])+(p1[2]+p1[3])) + ((p1[4]+p1[5])+(p1[6]+p1[7])))
                 +  (((p1[8]+p1[9])+(p1[10]+p1[11])) + ((p1[12]+p1[13])+(p1[14]+p1[15]))));
        ls += __shfl_xor(ls, 32, 64);
        lsum += ls;

        // ---- pack both P tiles ----
        u32 a0 = cvtpk(p0[0],  p0[1]),  a2 = cvtpk(p0[4],  p0[5]);  plswap(a0, a2);
        u32 a1 = cvtpk(p0[2],  p0[3]),  a3 = cvtpk(p0[6],  p0[7]);  plswap(a1, a3);
        u32 a4 = cvtpk(p0[8],  p0[9]),  a6 = cvtpk(p0[12], p0[13]); plswap(a4, a6);
        u32 a5 = cvtpk(p0[10], p0[11]), a7 = cvtpk(p0[14], p0[15]); plswap(a5, a7);
        u32 c0 = cvtpk(p1[0],  p1[1]),  c2 = cvtpk(p1[4],  p1[5]);  plswap(c0, c2);
        u32 c1 = cvtpk(p1[2],  p1[3]),  c3 = cvtpk(p1[6],  p1[7]);  plswap(c1, c3);
        u32 c4 = cvtpk(p1[8],  p1[9]),  c6 = cvtpk(p1[12], p1[13]); plswap(c4, c6);
        u32 c5 = cvtpk(p1[10], p1[11]), c7 = cvtpk(p1[14], p1[15]); plswap(c5, c7);
        union { u32 wd[4]; bf16x8 v; } f0, f1, g0, g1;
        f0.wd[0] = a0; f0.wd[1] = a1; f0.wd[2] = a2; f0.wd[3] = a3;
        f1.wd[0] = a4; f1.wd[1] = a5; f1.wd[2] = a6; f1.wd[3] = a7;
        g0.wd[0] = c0; g0.wd[1] = c1; g0.wd[2] = c2; g0.wd[3] = c3;
        g1.wd[0] = c4; g1.wd[1] = c5; g1.wd[2] = c6; g1.wd[3] = c7;

        // ---- PV for both tiles ----
        bf16x8 vf0[4], vf1[4];
        vf0[0] = *(const bf16x8*)(tb0 + voff0);
        vf0[1] = *(const bf16x8*)(tb0 + voff0 + 16);
        vf0[2] = *(const bf16x8*)(tb0 + voff1);
        vf0[3] = *(const bf16x8*)(tb0 + voff1 + 16);
        vf1[0] = *(const bf16x8*)(tb1 + voff0);
        vf1[1] = *(const bf16x8*)(tb1 + voff0 + 16);
        vf1[2] = *(const bf16x8*)(tb1 + voff1);
        vf1[3] = *(const bf16x8*)(tb1 + voff1 + 16);
        __builtin_amdgcn_s_setprio(1);
        o0 = MFMA32(vf0[0], f0.v, o0);
        o1 = MFMA32(vf0[2], f0.v, o1);
        o0 = MFMA32(vf0[1], f1.v, o0);
        o1 = MFMA32(vf0[3], f1.v, o1);
        o0 = MFMA32(vf1[0], g0.v, o0);
        o1 = MFMA32(vf1[2], g0.v, o1);
        o0 = MFMA32(vf1[1], g1.v, o0);
        o1 = MFMA32(vf1[3], g1.v, o1);
        __builtin_amdgcn_s_setprio(0);
    };

    bf16x8 kA0[4], kA1[4], kB0[4], kB1[4];
    LOADK(0, kA0, kA1);
    int st = 0;
    while (true) {
        if (st + 1 < nst) LOADK(st + 1, kB0, kB1);
        step(st, kA0, kA1);
        if (++st >= nst) break;
        if (st + 1 < nst) LOADK(st + 1, kA0, kA1);
        step(st, kB0, kB1);
        if (++st >= nst) break;
    }
#undef LOADK

    float inv = 1.0f / lsum;
    u16* ob = Out + ((size_t)(b * N_ + i0 + lo)) * INNER_ + h * DH_;
#pragma unroll
    for (int dd = 0; dd < 2; ++dd)
#pragma unroll
        for (int g = 0; g < 4; ++g) {
            int d0 = dd * 32 + 8 * g + 4 * hi;
            float e0 = (dd ? o1[4*g+0] : o0[4*g+0]) * inv;
            float e1 = (dd ? o1[4*g+1] : o0[4*g+1]) * inv;
            float e2 = (dd ? o1[4*g+2] : o0[4*g+2]) * inv;
            float e3 = (dd ? o1[4*g+3] : o0[4*g+3]) * inv;
            ushort4 u; u.x = f2bf(e0); u.y = f2bf(e1); u.z = f2bf(e2); u.w = f2bf(e3);
            *(ushort4*)(ob + d0) = u;
        }
}

// ---------------- launch ----------------
extern "C" void kernel_launch(void* const* d_in, const int* in_sizes, int n_in,
                              void* d_out, int out_size, void* d_ws, size_t ws_size,
                              hipStream_t stream) {
    const float* x       = (const float*)d_in[0];
    const void*  maskraw = d_in[1];
    const float* g_in    = (const float*)d_in[2];
    const float* Wq      = (const float*)d_in[3];
    const float* Wkv     = (const float*)d_in[4];
    const float* nullkv  = (const float*)d_in[5];
    const float* Wo      = (const float*)d_in[6];
    const float* g_out   = (const float*)d_in[7];
    float* out = (float*)d_out;

    char* ws = (char*)d_ws;
    size_t off = 0;
    auto alloc = [&](size_t bytes) {
        void* p = ws + off;
        off += (bytes + 255) & ~(size_t)255;
        return p;
    };
    u32* vbits  = (u32*)alloc((size_t)B_ * NW_ * 4);
    u16* wq16   = (u16*)alloc((size_t)INNER_ * DIM_ * 2);
    u16* wkv16  = (u16*)alloc((size_t)128 * DIM_ * 2);
    u16* wo16   = (u16*)alloc((size_t)DIM_ * INNER_ * 2);
    u16* bufA   = (u16*)alloc((size_t)ROWS_ * DIM_ * 2);   // xn, later attn out
    u16* xb     = (u16*)alloc((size_t)ROWS_ * DIM_ * 2);   // bf16 copy of x
    u16* bufC   = (u16*)alloc((size_t)ROWS_ * INNER_ * 2); // q, later o-proj out
    float* kvf  = (float*)alloc((size_t)ROWS_ * 128 * 4);
    u16* KVt    = (u16*)alloc((size_t)B_ * NTILE_ * TILE_ELEMS_ * 2);

    // fused: build_bits (2) + cvt_w (2176) + ln0 (8192)
    prep<<<2 + 2176 + ROWS_, 256, 0, stream>>>(
        maskraw, vbits, Wq, Wkv, Wo, wq16, wkv16, wo16, x, g_in, bufA, xb);

    proj_fused<<<dim3(9, ROWS_ / 128), 256, 0, stream>>>(
        bufA, xb, wq16, wkv16, bufC, kvf);

    build_kv<<<dim3(NTILE_, B_), 256, 0, stream>>>(kvf, nullkv, KVt);

    attn_un<<<1024, 256, 0, stream>>>(bufC, KVt, vbits, bufA);

    gemm_o<<<dim3(DIM_ / 128, ROWS_ / 128), 256, 0, stream>>>(bufA, wo16, bufC);

    ln_out<<<ROWS_, 256, 0, stream>>>(bufC, g_out, out);
}

// Round 23
// 147.853 us; speedup vs baseline: 1.0148x; 1.0148x over previous
//
#include <hip/hip_runtime.h>
#include <hip/hip_bf16.h>

#define B_     8
#define N_     1024
#define DIM_   1024
#define HEADS_ 16
#define DH_    64
#define INNER_ 1024
#define NKEY_  1025
#define NTILE_ 34        // kv tiles of 32 keys (33 real + 1 phantom zero tile)
#define NW_    34        // vbits words per batch (word 33 = 0)
#define ROWS_  8192
#define EPS_   1e-5f
// DIM_HEAD^-0.5 * log2(e): softmax done in exp2 domain; ALPHA/pb-relax cancels
#define QK_SCALE_ 0.1803368801111f
#define TILE_ELEMS_ 4096   // per (b,kt): 2048 K [j][d] + 2048 V^T [d][j]

typedef unsigned short u16;
typedef unsigned char  u8;
typedef unsigned int   u32;
typedef __attribute__((ext_vector_type(8)))  short bf16x8;
typedef __attribute__((ext_vector_type(4)))  float f32x4;
typedef __attribute__((ext_vector_type(16))) float f32x16;

__device__ __forceinline__ float bf2f(u16 u) {
    unsigned int x = ((unsigned int)u) << 16;
    return __uint_as_float(x);
}
__device__ __forceinline__ u16 f2bf(float f) {
    unsigned int x = __float_as_uint(f);
    x += 0x7FFFu + ((x >> 16) & 1u);   // RNE
    return (u16)(x >> 16);
}
__device__ __forceinline__ float max3f(float a, float b, float c) {
    return fmaxf(fmaxf(a, b), c);      // fuses to v_max3_f32
}
// 2^x via v_exp_f32 (ISA: D = 2^S0). Avoids glibc __exp2f macro collision.
__device__ __forceinline__ float exp2fast(float x) {
    float r;
    asm("v_exp_f32 %0, %1" : "=v"(r) : "v"(x));
    return r;
}

#define MFMA16(a, b, c) __builtin_amdgcn_mfma_f32_16x16x32_bf16((a), (b), (c), 0, 0, 0)
#define MFMA32(a, b, c) __builtin_amdgcn_mfma_f32_32x32x16_bf16((a), (b), (c), 0, 0, 0)

__device__ __forceinline__ void gload16(const void* g, void* l) {
    __builtin_amdgcn_global_load_lds(
        (const __attribute__((address_space(1))) unsigned int*)g,
        (__attribute__((address_space(3))) unsigned int*)l, 16, 0, 0);
}

__device__ __forceinline__ u32 cvtpk(float lo, float hi) {
    u32 r;
    asm("v_cvt_pk_bf16_f32 %0, %1, %2" : "=v"(r) : "v"(lo), "v"(hi));
    return r;
}
__device__ __forceinline__ void plswap(u32& a, u32& b) {
    asm volatile("v_permlane32_swap_b32 %0, %1" : "+v"(a), "+v"(b));
}

// ---------------- fused prep: build_bits (2 blocks) + cvt_w (2176) + ln0 (8192) --
// The three heads are mutually independent; merged to cut two graph-node gaps.
// Block-uniform branch on blockIdx.x range, so no divergence.
__global__ __launch_bounds__(256)
void prep(const void* __restrict__ mraw, u32* __restrict__ vbits,
          const float* __restrict__ wq, const float* __restrict__ wkv,
          const float* __restrict__ wo, u16* __restrict__ q16,
          u16* __restrict__ kv16, u16* __restrict__ o16,
          const float* __restrict__ x, const float* __restrict__ g_in,
          u16* __restrict__ xn, u16* __restrict__ xb) {
    const int bx = blockIdx.x;
    const int t  = threadIdx.x;
    if (bx < 2) {
        // ---- build_bits: mask -> visibility bitmask (format detected inline) ----
        int tid = bx * 256 + t;
        if (tid >= B_ * NW_) return;
        const unsigned int* mw = (const unsigned int*)mraw;
        int f = 0;  // 0=int32, 1=bytes(bool), 2=float32
        for (int i = 0; i < 64; ++i) {
            unsigned int w = mw[i];
            if (w == 0x3F800000u) { f = 2; break; }
            if (w > 1u) f = 1;
        }
        int b = tid / NW_, wq_ = tid - b * NW_;
        u32 bits = 0;
        for (int i = 0; i < 32; ++i) {
            int jp = wq_ * 32 + i;
            bool vis;
            if (jp == 0) vis = true;
            else if (jp < NKEY_) {
                int idx = b * N_ + jp - 1;
                if (f == 0)      vis = ((const int*)mraw)[idx] != 0;
                else if (f == 1) vis = ((const u8*)mraw)[idx] != 0;
                else             vis = ((const float*)mraw)[idx] != 0.0f;
            } else vis = false;
            if (vis) bits |= (1u << i);
        }
        vbits[tid] = bits;
    } else if (bx < 2 + 2176) {
        // ---- cvt_w: merged f32 -> bf16 weight convert ----
        int i = (bx - 2) * 256 + t;   // unit = 4 elems
        const int NQ = INNER_ * DIM_ / 4, NKV = 128 * DIM_ / 4, NO = DIM_ * INNER_ / 4;
        const float* src; u16* dst; int off;
        if (i < NQ)            { src = wq;  dst = q16;  off = i; }
        else if (i < NQ + NKV) { src = wkv; dst = kv16; off = i - NQ; }
        else if (i < NQ + NKV + NO) { src = wo; dst = o16; off = i - NQ - NKV; }
        else return;
        float4 v = ((const float4*)src)[off];
        ushort4 u; u.x = f2bf(v.x); u.y = f2bf(v.y); u.z = f2bf(v.z); u.w = f2bf(v.w);
        ((ushort4*)dst)[off] = u;
    } else {
        // ---- ln_rows<0>: f32 in -> bf16 LN out + bf16 raw copy ----
        int row = bx - (2 + 2176);
        float4 v = ((const float4*)(x + (size_t)row * DIM_))[t];
        float v0 = v.x, v1 = v.y, v2 = v.z, v3 = v.w;
        float s  = v0 + v1 + v2 + v3;
        float ss = v0*v0 + v1*v1 + v2*v2 + v3*v3;
#pragma unroll
        for (int off = 32; off > 0; off >>= 1) {
            s  += __shfl_down(s,  off, 64);
            ss += __shfl_down(ss, off, 64);
        }
        __shared__ float red[10];
        int wid = t >> 6, lane = t & 63;
        if (lane == 0) { red[wid] = s; red[4 + wid] = ss; }
        __syncthreads();
        if (t == 0) {
            float S  = red[0] + red[1] + red[2] + red[3];
            float SS = red[4] + red[5] + red[6] + red[7];
            float mean = S * (1.0f / DIM_);
            float var  = SS * (1.0f / DIM_) - mean * mean;
            red[8] = mean;
            red[9] = rsqrtf(var + EPS_);
        }
        __syncthreads();
        float mean = red[8], rs = red[9];
        float4 gv = ((const float4*)g_in)[t];
        float o0 = (v0 - mean) * rs * gv.x;
        float o1 = (v1 - mean) * rs * gv.y;
        float o2 = (v2 - mean) * rs * gv.z;
        float o3 = (v3 - mean) * rs * gv.w;
        ushort4 u; u.x = f2bf(o0); u.y = f2bf(o1); u.z = f2bf(o2); u.w = f2bf(o3);
        ((ushort4*)(xn + (size_t)row * DIM_))[t] = u;
        ushort4 rw; rw.x = f2bf(v0); rw.y = f2bf(v1); rw.z = f2bf(v2); rw.w = f2bf(v3);
        ((ushort4*)(xb + (size_t)row * DIM_))[t] = rw;
    }
}

// ---------------- final layernorm: bf16 in -> f32 out ----------------
__global__ __launch_bounds__(256)
void ln_out(const u16* __restrict__ xv, const float* __restrict__ g,
            float* __restrict__ outv) {
    int row = blockIdx.x;
    int t = threadIdx.x;
    ushort4 u = ((const ushort4*)(xv + (size_t)row * DIM_))[t];
    float v0 = bf2f(u.x), v1 = bf2f(u.y), v2 = bf2f(u.z), v3 = bf2f(u.w);
    float s  = v0 + v1 + v2 + v3;
    float ss = v0*v0 + v1*v1 + v2*v2 + v3*v3;
#pragma unroll
    for (int off = 32; off > 0; off >>= 1) {
        s  += __shfl_down(s,  off, 64);
        ss += __shfl_down(ss, off, 64);
    }
    __shared__ float red[10];
    int wid = t >> 6, lane = t & 63;
    if (lane == 0) { red[wid] = s; red[4 + wid] = ss; }
    __syncthreads();
    if (t == 0) {
        float S  = red[0] + red[1] + red[2] + red[3];
        float SS = red[4] + red[5] + red[6] + red[7];
        float mean = S * (1.0f / DIM_);
        float var  = SS * (1.0f / DIM_) - mean * mean;
        red[8] = mean;
        red[9] = rsqrtf(var + EPS_);
    }
    __syncthreads();
    float mean = red[8], rs = red[9];
    float4 gv = ((const float4*)g)[t];
    float4 o;
    o.x = (v0 - mean) * rs * gv.x;
    o.y = (v1 - mean) * rs * gv.y;
    o.z = (v2 - mean) * rs * gv.z;
    o.w = (v3 - mean) * rs * gv.w;
    ((float4*)(outv + (size_t)row * DIM_))[t] = o;
}

// ---------------- fused Q-proj + KV-proj (m97 structure, BK=32, K=1024) ---------
// XCD-chunked remap: 576 blocks; id%8 == XCD, each XCD gets 72 consecutive wids
// = 8 consecutive A row-panels (2 MB, L2-fits) x all 9 B panels -> staging
// loads hit the local L2 instead of L3, shortening the vmcnt(0) barrier drain.
__global__ __launch_bounds__(256)
void proj_fused(const u16* __restrict__ xn, const u16* __restrict__ xraw,
                const u16* __restrict__ wq, const u16* __restrict__ wkv,
                u16* __restrict__ qout, float* __restrict__ kvout) {
    __shared__ u16 As[128 * 32];
    __shared__ u16 Bs[128 * 32];
    const int id  = blockIdx.x + 9 * blockIdx.y;      // 0..575
    const int wid = (id & 7) * 72 + (id >> 3);        // bijective (576 = 8*72)
    const int bxx = wid % 9, byy = wid / 9;
    const bool iskv = (bxx == 8);
    const u16* A  = iskv ? xraw : xn;
    const u16* Bt = iskv ? wkv : wq;
    const int  n0 = iskv ? 0 : bxx * 128;
    const float scale = iskv ? 1.0f : QK_SCALE_;
    const int t = threadIdx.x;
    const int w = t >> 6, l = t & 63;
    const int col = l & 15, rg = l >> 4;
    const int wm = (w >> 1) * 64, wn = (w & 1) * 64;
    const int m0 = byy * 128;
    const int slr = l >> 2;
    const int slc = (l & 3) * 8;
    f32x4 acc[4][4];
#pragma unroll
    for (int i = 0; i < 4; ++i)
#pragma unroll
        for (int j = 0; j < 4; ++j) acc[i][j] = f32x4{0.f, 0.f, 0.f, 0.f};

    const u16* Abase = A  + (size_t)m0 * DIM_;
    const u16* Bbase = Bt + (size_t)n0 * DIM_;
    for (int k0 = 0; k0 < DIM_; k0 += 32) {
        __syncthreads();
#pragma unroll
        for (int p = 0; p < 2; ++p) {
            int rb = w * 2 + p;
            gload16(Abase + (size_t)(rb * 16 + slr) * DIM_ + k0 + slc, &As[rb * 512]);
            gload16(Bbase + (size_t)(rb * 16 + slr) * DIM_ + k0 + slc, &Bs[rb * 512]);
        }
        __syncthreads();
        bf16x8 af[4], bf4[4];
#pragma unroll
        for (int mi = 0; mi < 4; ++mi)
            af[mi] = *(const bf16x8*)&As[(wm + mi * 16 + col) * 32 + rg * 8];
#pragma unroll
        for (int ni = 0; ni < 4; ++ni)
            bf4[ni] = *(const bf16x8*)&Bs[(wn + ni * 16 + col) * 32 + rg * 8];
#pragma unroll
        for (int mi = 0; mi < 4; ++mi)
#pragma unroll
            for (int ni = 0; ni < 4; ++ni)
                acc[mi][ni] = MFMA16(af[mi], bf4[ni], acc[mi][ni]);
    }
#pragma unroll
    for (int mi = 0; mi < 4; ++mi)
#pragma unroll
        for (int ni = 0; ni < 4; ++ni)
#pragma unroll
            for (int r = 0; r < 4; ++r) {
                size_t row = (size_t)(m0 + wm + mi * 16 + rg * 4 + r);
                int c = n0 + wn + ni * 16 + col;
                float vv = acc[mi][ni][r] * scale;
                if (iskv) kvout[row * 128 + c] = vv;
                else      qout[row * INNER_ + c] = f2bf(vv);
            }
}

// ---------------- MFMA GEMM for O-projection (BK=32, XCD-chunked remap) --------
__global__ __launch_bounds__(256)
void gemm_o(const u16* __restrict__ A, const u16* __restrict__ Bt,
            u16* __restrict__ Cv) {
    __shared__ u16 As[128 * 32];
    __shared__ u16 Bs[128 * 32];
    const int id  = blockIdx.x + 8 * blockIdx.y;      // 0..511
    const int wid = (id & 7) * 64 + (id >> 3);        // bijective (512 = 8*64)
    const int bxx = wid & 7, byy = wid >> 3;
    const int t = threadIdx.x;
    const int w = t >> 6, l = t & 63;
    const int col = l & 15, rg = l >> 4;
    const int wm = (w >> 1) * 64, wn = (w & 1) * 64;
    const int m0 = byy * 128, n0 = bxx * 128;
    const int slr = l >> 2;
    const int slc = (l & 3) * 8;
    f32x4 acc[4][4];
#pragma unroll
    for (int i = 0; i < 4; ++i)
#pragma unroll
        for (int j = 0; j < 4; ++j) acc[i][j] = f32x4{0.f, 0.f, 0.f, 0.f};
    const u16* Abase = A  + (size_t)m0 * INNER_;
    const u16* Bbase = Bt + (size_t)n0 * INNER_;
    for (int k0 = 0; k0 < INNER_; k0 += 32) {
        __syncthreads();
#pragma unroll
        for (int p = 0; p < 2; ++p) {
            int rb = w * 2 + p;
            gload16(Abase + (size_t)(rb * 16 + slr) * INNER_ + k0 + slc, &As[rb * 512]);
            gload16(Bbase + (size_t)(rb * 16 + slr) * INNER_ + k0 + slc, &Bs[rb * 512]);
        }
        __syncthreads();
        bf16x8 af[4], bf4[4];
#pragma unroll
        for (int mi = 0; mi < 4; ++mi)
            af[mi] = *(const bf16x8*)&As[(wm + mi * 16 + col) * 32 + rg * 8];
#pragma unroll
        for (int ni = 0; ni < 4; ++ni)
            bf4[ni] = *(const bf16x8*)&Bs[(wn + ni * 16 + col) * 32 + rg * 8];
#pragma unroll
        for (int mi = 0; mi < 4; ++mi)
#pragma unroll
            for (int ni = 0; ni < 4; ++ni)
                acc[mi][ni] = MFMA16(af[mi], bf4[ni], acc[mi][ni]);
    }
#pragma unroll
    for (int mi = 0; mi < 4; ++mi)
#pragma unroll
        for (int ni = 0; ni < 4; ++ni)
#pragma unroll
            for (int r = 0; r < 4; ++r) {
                size_t row = (size_t)(m0 + wm + mi * 16 + rg * 4 + r);
                int c = n0 + wn + ni * 16 + col;
                Cv[row * DIM_ + c] = f2bf(acc[mi][ni][r]);
            }
}

// ---------------- build per-tile K/V: [b][kt]{ K[32][64], V^T[64][32] } ----------------
__global__ __launch_bounds__(256)
void build_kv(const float* __restrict__ kvf, const float* __restrict__ nullkv,
              u16* __restrict__ KVt) {
    const int kt = blockIdx.x, b = blockIdx.y;
    const int t = threadIdx.x;
    const int k0 = kt * 32;
    u16* base = KVt + ((size_t)b * NTILE_ + kt) * TILE_ELEMS_;
    // K part: [j][d], 8 elems/thread, contiguous dest
    {
        int j = t >> 3;
        int d0 = (t & 7) * 8;
        int jp = k0 + j;
        float v[8];
        if (jp == 0) {
#pragma unroll
            for (int i = 0; i < 8; ++i) v[i] = nullkv[d0 + i];
        } else if (jp <= N_) {
            const float* r = kvf + ((size_t)b * N_ + jp - 1) * 128 + d0;
            float4 a = ((const float4*)r)[0], c = ((const float4*)r)[1];
            v[0]=a.x; v[1]=a.y; v[2]=a.z; v[3]=a.w; v[4]=c.x; v[5]=c.y; v[6]=c.z; v[7]=c.w;
        } else {
#pragma unroll
            for (int i = 0; i < 8; ++i) v[i] = 0.f;
        }
        ushort4 u0, u1;
        u0.x=f2bf(v[0]); u0.y=f2bf(v[1]); u0.z=f2bf(v[2]); u0.w=f2bf(v[3]);
        u1.x=f2bf(v[4]); u1.y=f2bf(v[5]); u1.z=f2bf(v[6]); u1.w=f2bf(v[7]);
        *(ushort4*)(base + j * 64 + d0)     = u0;
        *(ushort4*)(base + j * 64 + d0 + 4) = u1;
    }
    // V part: [d][j], 8 elems/thread (8 consecutive j for one d)
    {
        int d = t >> 2;
        int j0 = (t & 3) * 8;
        u16 o8[8];
#pragma unroll
        for (int i = 0; i < 8; ++i) {
            int jp = k0 + j0 + i;
            float val = 0.f;
            if (jp == 0) val = nullkv[64 + d];
            else if (jp <= N_) val = kvf[((size_t)b * N_ + jp - 1) * 128 + 64 + d];
            o8[i] = f2bf(val);
        }
        u16* dst = base + 2048 + d * 32 + j0;
        ushort4 u0, u1;
        u0.x=o8[0]; u0.y=o8[1]; u0.z=o8[2]; u0.w=o8[3];
        u1.x=o8[4]; u1.y=o8[5]; u1.z=o8[6]; u1.w=o8[7];
        *(ushort4*)dst = u0;
        *(ushort4*)(dst + 4) = u1;
    }
}

// ---------------- unpaired no-LDS flash attention, KVBLK=64, exp2 softmax -------
// XCD-affinity: b = fid & 7; LPT: qt = 31 - (fid>>5)   (round-14 proven decode)
__global__ __launch_bounds__(256)
void attn_un(const u16* __restrict__ Q, const u16* __restrict__ KVt,
             const u32* __restrict__ vbits, u16* __restrict__ Out) {
    const int t = threadIdx.x;
    const int w = t >> 6, l = t & 63;
    const int lo = l & 31, hi = l >> 5;
    const int fid = blockIdx.x;
    const int b  = fid & 7;                   // == XCD id (blockIdx % 8)
    const int hg = (fid >> 3) & 3;
    const int qt = 31 - (fid >> 5);           // longest first (LPT)
    const int h = hg * 4 + w;
    const int i0 = qt * 32;
    const int nst = (qt + 3) >> 1;            // super-steps of 64 keys

    bf16x8 qf[4];
    {
        const u16* qp = Q + ((size_t)(b * N_ + i0 + lo)) * INNER_ + h * DH_ + hi * 8;
#pragma unroll
        for (int dt = 0; dt < 4; ++dt) qf[dt] = *(const bf16x8*)(qp + dt * 16);
    }
    f32x16 o0, o1;
#pragma unroll
    for (int i = 0; i < 16; ++i) { o0[i] = 0.f; o1[i] = 0.f; }
    float m = -3.0e38f, lsum = 0.f;

    const u16* tbase = KVt + (size_t)b * NTILE_ * TILE_ELEMS_;
    const u32* vbp = vbits + b * NW_;
    const int koff  = lo * 64 + hi * 8;
    const int voff0 = 2048 + lo * 32 + hi * 8;
    const int voff1 = 2048 + (lo + 32) * 32 + hi * 8;

    for (int st = 0; st < nst; ++st) {
        const int kt0 = st * 2, kt1 = st * 2 + 1;
        const u16* tb0 = tbase + (size_t)kt0 * TILE_ELEMS_;
        const u16* tb1 = tbase + (size_t)kt1 * TILE_ELEMS_;
        bf16x8 kf0[4], kf1[4];
        kf0[0] = *(const bf16x8*)(tb0 + koff);
        kf0[1] = *(const bf16x8*)(tb0 + koff + 16);
        kf0[2] = *(const bf16x8*)(tb0 + koff + 32);
        kf0[3] = *(const bf16x8*)(tb0 + koff + 48);
        kf1[0] = *(const bf16x8*)(tb1 + koff);
        kf1[1] = *(const bf16x8*)(tb1 + koff + 16);
        kf1[2] = *(const bf16x8*)(tb1 + koff + 32);
        kf1[3] = *(const bf16x8*)(tb1 + koff + 48);

        u32 vb0 = vbp[kt0], vb1 = vbp[kt1];
        union { u32 wd[4]; bf16x8 v; } bias0, bias1, ones;
        bias0.wd[0] = (hi == 0 && !((vb0 >> lo) & 1u)) ? 0xC6E0u : 0u; // bf16 -28672
        bias0.wd[1] = 0; bias0.wd[2] = 0; bias0.wd[3] = 0;
        bias1.wd[0] = (hi == 0 && !((vb1 >> lo) & 1u)) ? 0xC6E0u : 0u;
        bias1.wd[1] = 0; bias1.wd[2] = 0; bias1.wd[3] = 0;
        ones.wd[0] = (hi == 0) ? 0x3F80u : 0u;                         // bf16 1.0
        ones.wd[1] = 0; ones.wd[2] = 0; ones.wd[3] = 0;

        f32x16 s0, s1;
        __builtin_amdgcn_s_setprio(1);
#pragma unroll
        for (int i = 0; i < 16; ++i) { s0[i] = 0.f; s1[i] = 0.f; }
        s0 = MFMA32(kf0[0], qf[0], s0);
        s1 = MFMA32(kf1[0], qf[0], s1);
        s0 = MFMA32(kf0[1], qf[1], s0);
        s1 = MFMA32(kf1[1], qf[1], s1);
        s0 = MFMA32(kf0[2], qf[2], s0);
        s1 = MFMA32(kf1[2], qf[2], s1);
        s0 = MFMA32(kf0[3], qf[3], s0);
        s1 = MFMA32(kf1[3], qf[3], s1);
        s0 = MFMA32(bias0.v, ones.v, s0);
        s1 = MFMA32(bias1.v, ones.v, s1);
        __builtin_amdgcn_s_setprio(0);

        // ---- one softmax pass over 32 scores ----
        float t0 = max3f(s0[0],  s0[1],  s0[2]);
        float t1 = max3f(s0[3],  s0[4],  s0[5]);
        float t2 = max3f(s0[6],  s0[7],  s0[8]);
        float t3 = max3f(s0[9],  s0[10], s0[11]);
        float t4 = max3f(s0[12], s0[13], s0[14]);
        float u0 = max3f(s1[0],  s1[1],  s1[2]);
        float u1 = max3f(s1[3],  s1[4],  s1[5]);
        float u2 = max3f(s1[6],  s1[7],  s1[8]);
        float u3 = max3f(s1[9],  s1[10], s1[11]);
        float u4 = max3f(s1[12], s1[13], s1[14]);
        float mt = fmaxf(max3f(max3f(t0, t1, t2), max3f(t3, t4, s0[15]),
                               max3f(u0, u1, u2)),
                         max3f(u3, u4, s1[15]));
        mt = fmaxf(mt, __shfl_xor(mt, 32, 64));
        if (!__all(mt <= m + 8.0f)) {          // defer-max (T13), exp2 domain
            float mn = fmaxf(m, mt);
            float c = exp2fast(m - mn);
            lsum *= c;
#pragma unroll
            for (int i = 0; i < 16; ++i) { o0[i] *= c; o1[i] *= c; }
            m = mn;
        }
        float p0[16], p1[16];
#pragma unroll
        for (int r = 0; r < 16; ++r) p0[r] = exp2fast(s0[r] - m);
#pragma unroll
        for (int r = 0; r < 16; ++r) p1[r] = exp2fast(s1[r] - m);
        if (kt0 >= qt) {
            int lim0 = i0 + lo + 1 - kt0 * 32 - 4 * hi;
#pragma unroll
            for (int r = 0; r < 16; ++r)
                if (((r & 3) + 8 * (r >> 2)) > lim0) p0[r] = 0.f;
        }
        if (kt1 >= qt) {
            int lim1 = i0 + lo + 1 - kt1 * 32 - 4 * hi;
#pragma unroll
            for (int r = 0; r < 16; ++r)
                if (((r & 3) + 8 * (r >> 2)) > lim1) p1[r] = 0.f;
        }
        float ls = ((((p0[0]+p0[1])+(p0[2]+p0[3])) + ((p0[4]+p0[5])+(p0[6]+p0[7])))
                 +  (((p0[8]+p0[9])+(p0[10]+p0[11])) + ((p0[12]+p0[13])+(p0[14]+p0[15]))))
                 + ((((p1[0]+p1[1])+(p1[2]+p1[3])) + ((p1[4]+p1[5])+(p1[6]+p1[7])))
                 +  (((p1[8]+p1[9])+(p1[10]+p1[11])) + ((p1[12]+p1[13])+(p1[14]+p1[15]))));
        ls += __shfl_xor(ls, 32, 64);
        lsum += ls;

        // ---- pack both P tiles ----
        u32 a0 = cvtpk(p0[0],  p0[1]),  a2 = cvtpk(p0[4],  p0[5]);  plswap(a0, a2);
        u32 a1 = cvtpk(p0[2],  p0[3]),  a3 = cvtpk(p0[6],  p0[7]);  plswap(a1, a3);
        u32 a4 = cvtpk(p0[8],  p0[9]),  a6 = cvtpk(p0[12], p0[13]); plswap(a4, a6);
        u32 a5 = cvtpk(p0[10], p0[11]), a7 = cvtpk(p0[14], p0[15]); plswap(a5, a7);
        u32 c0 = cvtpk(p1[0],  p1[1]),  c2 = cvtpk(p1[4],  p1[5]);  plswap(c0, c2);
        u32 c1 = cvtpk(p1[2],  p1[3]),  c3 = cvtpk(p1[6],  p1[7]);  plswap(c1, c3);
        u32 c4 = cvtpk(p1[8],  p1[9]),  c6 = cvtpk(p1[12], p1[13]); plswap(c4, c6);
        u32 c5 = cvtpk(p1[10], p1[11]), c7 = cvtpk(p1[14], p1[15]); plswap(c5, c7);
        union { u32 wd[4]; bf16x8 v; } f0, f1, g0, g1;
        f0.wd[0] = a0; f0.wd[1] = a1; f0.wd[2] = a2; f0.wd[3] = a3;
        f1.wd[0] = a4; f1.wd[1] = a5; f1.wd[2] = a6; f1.wd[3] = a7;
        g0.wd[0] = c0; g0.wd[1] = c1; g0.wd[2] = c2; g0.wd[3] = c3;
        g1.wd[0] = c4; g1.wd[1] = c5; g1.wd[2] = c6; g1.wd[3] = c7;

        // ---- PV for both tiles ----
        bf16x8 vf0[4], vf1[4];
        vf0[0] = *(const bf16x8*)(tb0 + voff0);
        vf0[1] = *(const bf16x8*)(tb0 + voff0 + 16);
        vf0[2] = *(const bf16x8*)(tb0 + voff1);
        vf0[3] = *(const bf16x8*)(tb0 + voff1 + 16);
        vf1[0] = *(const bf16x8*)(tb1 + voff0);
        vf1[1] = *(const bf16x8*)(tb1 + voff0 + 16);
        vf1[2] = *(const bf16x8*)(tb1 + voff1);
        vf1[3] = *(const bf16x8*)(tb1 + voff1 + 16);
        __builtin_amdgcn_s_setprio(1);
        o0 = MFMA32(vf0[0], f0.v, o0);
        o1 = MFMA32(vf0[2], f0.v, o1);
        o0 = MFMA32(vf0[1], f1.v, o0);
        o1 = MFMA32(vf0[3], f1.v, o1);
        o0 = MFMA32(vf1[0], g0.v, o0);
        o1 = MFMA32(vf1[2], g0.v, o1);
        o0 = MFMA32(vf1[1], g1.v, o0);
        o1 = MFMA32(vf1[3], g1.v, o1);
        __builtin_amdgcn_s_setprio(0);
    }

    float inv = 1.0f / lsum;
    u16* ob = Out + ((size_t)(b * N_ + i0 + lo)) * INNER_ + h * DH_;
#pragma unroll
    for (int dd = 0; dd < 2; ++dd)
#pragma unroll
        for (int g = 0; g < 4; ++g) {
            int d0 = dd * 32 + 8 * g + 4 * hi;
            float e0 = (dd ? o1[4*g+0] : o0[4*g+0]) * inv;
            float e1 = (dd ? o1[4*g+1] : o0[4*g+1]) * inv;
            float e2 = (dd ? o1[4*g+2] : o0[4*g+2]) * inv;
            float e3 = (dd ? o1[4*g+3] : o0[4*g+3]) * inv;
            ushort4 u; u.x = f2bf(e0); u.y = f2bf(e1); u.z = f2bf(e2); u.w = f2bf(e3);
            *(ushort4*)(ob + d0) = u;
        }
}

// ---------------- launch ----------------
extern "C" void kernel_launch(void* const* d_in, const int* in_sizes, int n_in,
                              void* d_out, int out_size, void* d_ws, size_t ws_size,
                              hipStream_t stream) {
    const float* x       = (const float*)d_in[0];
    const void*  maskraw = d_in[1];
    const float* g_in    = (const float*)d_in[2];
    const float* Wq      = (const float*)d_in[3];
    const float* Wkv     = (const float*)d_in[4];
    const float* nullkv  = (const float*)d_in[5];
    const float* Wo      = (const float*)d_in[6];
    const float* g_out   = (const float*)d_in[7];
    float* out = (float*)d_out;

    char* ws = (char*)d_ws;
    size_t off = 0;
    auto alloc = [&](size_t bytes) {
        void* p = ws + off;
        off += (bytes + 255) & ~(size_t)255;
        return p;
    };
    u32* vbits  = (u32*)alloc((size_t)B_ * NW_ * 4);
    u16* wq16   = (u16*)alloc((size_t)INNER_ * DIM_ * 2);
    u16* wkv16  = (u16*)alloc((size_t)128 * DIM_ * 2);
    u16* wo16   = (u16*)alloc((size_t)DIM_ * INNER_ * 2);
    u16* bufA   = (u16*)alloc((size_t)ROWS_ * DIM_ * 2);   // xn, later attn out
    u16* xb     = (u16*)alloc((size_t)ROWS_ * DIM_ * 2);   // bf16 copy of x
    u16* bufC   = (u16*)alloc((size_t)ROWS_ * INNER_ * 2); // q, later o-proj out
    float* kvf  = (float*)alloc((size_t)ROWS_ * 128 * 4);
    u16* KVt    = (u16*)alloc((size_t)B_ * NTILE_ * TILE_ELEMS_ * 2);

    // fused: build_bits (2) + cvt_w (2176) + ln0 (8192)
    prep<<<2 + 2176 + ROWS_, 256, 0, stream>>>(
        maskraw, vbits, Wq, Wkv, Wo, wq16, wkv16, wo16, x, g_in, bufA, xb);

    proj_fused<<<dim3(9, ROWS_ / 128), 256, 0, stream>>>(
        bufA, xb, wq16, wkv16, bufC, kvf);

    build_kv<<<dim3(NTILE_, B_), 256, 0, stream>>>(kvf, nullkv, KVt);

    attn_un<<<1024, 256, 0, stream>>>(bufC, KVt, vbits, bufA);

    gemm_o<<<dim3(DIM_ / 128, ROWS_ / 128), 256, 0, stream>>>(bufA, wo16, bufC);

    ln_out<<<ROWS_, 256, 0, stream>>>(bufC, g_out, out);
}